// Round 7
// baseline (613.106 us; speedup 1.0000x reference)
//
#include <hip/hip_runtime.h>
#include <hip/hip_bf16.h>
#include <float.h>

#define N_NODES 8192
#define NEDGE   524288
#define IND     128
#define HID     256
#define OUTD    128
#define NHEAD   4
#define HD      64

typedef short short8 __attribute__((ext_vector_type(8)));
typedef short short4v __attribute__((ext_vector_type(4)));
typedef float f32x4  __attribute__((ext_vector_type(4)));
typedef float f32x16 __attribute__((ext_vector_type(16)));
typedef unsigned int u32x4 __attribute__((ext_vector_type(4)));

__device__ __forceinline__ float sigmoidf_(float x) { return 1.0f / (1.0f + expf(-x)); }

__device__ __forceinline__ unsigned short f2bf(float f) {
    __hip_bfloat16 b = __float2bfloat16(f);
    return __builtin_bit_cast(unsigned short, b);
}
__device__ __forceinline__ float bf2f(unsigned short u) {
    __hip_bfloat16 b = __builtin_bit_cast(__hip_bfloat16, u);
    return __bfloat162float(b);
}
__device__ __forceinline__ void split3(float x, unsigned short& a, unsigned short& b, unsigned short& c) {
    a = f2bf(x); float r = x - bf2f(a);
    b = f2bf(r); r = r - bf2f(b);
    c = f2bf(r);
}
__device__ __forceinline__ void split2(float x, unsigned short& a, unsigned short& b) {
    a = f2bf(x); float r = x - bf2f(a);
    b = f2bf(r);
}
__device__ __forceinline__ unsigned int cvtpk(float lo, float hi) {
    unsigned int r;
    asm("v_cvt_pk_bf16_f32 %0, %1, %2" : "=v"(r) : "v"(lo), "v"(hi));
    return r;
}
__device__ __forceinline__ void plswap(unsigned int& a, unsigned int& b) {
    asm volatile("v_permlane32_swap_b32 %0, %1" : "+v"(a), "+v"(b));
}
__device__ __forceinline__ void gll16(const void* g, void* l) {
    __builtin_amdgcn_global_load_lds(
        (const __attribute__((address_space(1))) void*)g,
        (__attribute__((address_space(3))) void*)l, 16, 0, 0);
}
__device__ __forceinline__ f32x16 mfma32(short8 a, short8 b, f32x16 c) {
    return __builtin_amdgcn_mfma_f32_32x32x16_bf16(a, b, c, 0, 0, 0);
}

// ---------------- CSR build ----------------
__global__ void hist_kernel(const int* __restrict__ ei, int* __restrict__ deg)
{
    int e = blockIdx.x * blockDim.x + threadIdx.x;
    if (e < NEDGE) atomicAdd(&deg[ei[NEDGE + e]], 1);
}

__global__ __launch_bounds__(1024) void scan_kernel(
    const int* __restrict__ deg, int* __restrict__ row_ptr, int* __restrict__ cursor)
{
    __shared__ int sh[1024];
    const int t = threadIdx.x;
    int v[8]; int s = 0;
    #pragma unroll
    for (int i = 0; i < 8; ++i) { v[i] = deg[t * 8 + i]; s += v[i]; }
    sh[t] = s; __syncthreads();
    for (int off = 1; off < 1024; off <<= 1) {
        int add = (t >= off) ? sh[t - off] : 0;
        __syncthreads();
        sh[t] += add;
        __syncthreads();
    }
    int base = sh[t] - s;
    #pragma unroll
    for (int i = 0; i < 8; ++i) {
        row_ptr[t * 8 + i] = base;
        cursor[t * 8 + i]  = base;
        base += v[i];
    }
    if (t == 1023) row_ptr[N_NODES] = base;
}

__global__ void scatter_kernel(const int* __restrict__ ei, int* __restrict__ cursor,
                               int* __restrict__ esrc)
{
    int e = blockIdx.x * blockDim.x + threadIdx.x;
    if (e < NEDGE) {
        int d = ei[NEDGE + e];
        int p = atomicAdd(&cursor[d], 1);
        esrc[p] = ei[e];
    }
}

// ---------------- split fp32 array -> 3 bf16 comps (comp stride = elems) ----------------
__global__ __launch_bounds__(256) void split_w_kernel(
    const float* __restrict__ w, unsigned short* __restrict__ Wc, int elems)
{
    const int i = (blockIdx.x * 256 + threadIdx.x) * 8;
    if (i >= elems) return;
    float4 a = *(const float4*)(w + i);
    float4 b = *(const float4*)(w + i + 4);
    float v[8] = {a.x, a.y, a.z, a.w, b.x, b.y, b.z, b.w};
    short8 c0, c1, c2;
    #pragma unroll
    for (int j = 0; j < 8; ++j) {
        unsigned short p, q, r;
        split3(v[j], p, q, r);
        c0[j] = (short)p; c1[j] = (short)q; c2[j] = (short)r;
    }
    *(short8*)(Wc + i) = c0;
    *(short8*)(Wc + elems + i) = c1;
    *(short8*)(Wc + 2 * elems + i) = c2;
}

// ---------------- GNN aggregate, XCD-affine column-sliced ----------------
// grid 8192 blocks: b&7 = XCD slot (slice = xs&3, half = xs>>2) -> each XCD's
// gather working set = 8192 x 64 cols x 4B = 2MB < 4MB L2.
__global__ __launch_bounds__(256) void aggregate_sliced_kernel(
    const float* __restrict__ hin, float* __restrict__ hout,
    const int* __restrict__ row_ptr, const int* __restrict__ esrc,
    const float* __restrict__ plas, const float* __restrict__ syn, int layer)
{
    const int b = blockIdx.x;
    const int xs = b & 7, g = b >> 3;
    const int slice = xs & 3, halfn = xs >> 2;
    const int t = threadIdx.x;
    const int dst = halfn * 4096 + g * 4 + (t >> 6);
    const int col = slice * 64 + (t & 63);
    const int st = row_ptr[dst], en = row_ptr[dst + 1];
    float a0 = 0.f, a1 = 0.f, a2 = 0.f, a3 = 0.f;
    int e = st;
    for (; e + 4 <= en; e += 4) {
        int s0 = esrc[e], s1 = esrc[e + 1], s2 = esrc[e + 2], s3 = esrc[e + 3];
        a0 += hin[(size_t)s0 * HID + col];
        a1 += hin[(size_t)s1 * HID + col];
        a2 += hin[(size_t)s2 * HID + col];
        a3 += hin[(size_t)s3 * HID + col];
    }
    float acc = (a0 + a1) + (a2 + a3);
    for (; e < en; ++e) acc += hin[(size_t)esrc[e] * HID + col];
    const float scale = sigmoidf_(plas[layer]) * sigmoidf_(syn[layer]);
    float x = acc * scale;
    hout[(size_t)dst * HID + col] = (x > 0.f) ? x : 0.01f * x;
}

// same, split-3 bf16 output (last layer)
__global__ __launch_bounds__(256) void aggregate_sliced_split_kernel(
    const float* __restrict__ hin,
    unsigned short* __restrict__ H0, unsigned short* __restrict__ H1,
    unsigned short* __restrict__ H2,
    const int* __restrict__ row_ptr, const int* __restrict__ esrc,
    const float* __restrict__ plas, const float* __restrict__ syn, int layer)
{
    const int b = blockIdx.x;
    const int xs = b & 7, g = b >> 3;
    const int slice = xs & 3, halfn = xs >> 2;
    const int t = threadIdx.x;
    const int dst = halfn * 4096 + g * 4 + (t >> 6);
    const int col = slice * 64 + (t & 63);
    const int st = row_ptr[dst], en = row_ptr[dst + 1];
    float a0 = 0.f, a1 = 0.f, a2 = 0.f, a3 = 0.f;
    int e = st;
    for (; e + 4 <= en; e += 4) {
        int s0 = esrc[e], s1 = esrc[e + 1], s2 = esrc[e + 2], s3 = esrc[e + 3];
        a0 += hin[(size_t)s0 * HID + col];
        a1 += hin[(size_t)s1 * HID + col];
        a2 += hin[(size_t)s2 * HID + col];
        a3 += hin[(size_t)s3 * HID + col];
    }
    float acc = (a0 + a1) + (a2 + a3);
    for (; e < en; ++e) acc += hin[(size_t)esrc[e] * HID + col];
    const float scale = sigmoidf_(plas[layer]) * sigmoidf_(syn[layer]);
    float x = acc * scale;
    x = (x > 0.f) ? x : 0.01f * x;
    unsigned short p, q, r;
    split3(x, p, q, r);
    H0[(size_t)dst * HID + col] = p;
    H1[(size_t)dst * HID + col] = q;
    H2[(size_t)dst * HID + col] = r;
}

// ---------------- MFMA split-precision GEMM: C[M,N] = A[M,K] W[N,K]^T + bias
// A pre-split (NA comps); W pre-split bf16 comps (stride NK). NT=6 or 3 terms.
template<int NT, int NA, bool SOUT>
__global__ __launch_bounds__(256) void mfma_gemm_kernel(
    const unsigned short* __restrict__ A0, const unsigned short* __restrict__ A1,
    const unsigned short* __restrict__ A2,
    const unsigned short* __restrict__ Wc, const float* __restrict__ bias,
    float* __restrict__ Cf, unsigned short* __restrict__ C0, unsigned short* __restrict__ C1,
    int M, int Nn, int K)
{
    const int t = threadIdx.x;
    const int wv = t >> 6, lane = t & 63;
    const int l31 = lane & 31, l5 = lane >> 5;
    const int wm = wv & 1, wn = wv >> 1;
    const int m0 = blockIdx.x * 64 + wm * 32;
    const int n0 = blockIdx.y * 64 + wn * 32;
    const int mrow = m0 + l31;
    const int nrow = n0 + l31;
    const size_t NK = (size_t)Nn * K;

    f32x16 o;
    #pragma unroll
    for (int r = 0; r < 16; ++r) o[r] = 0.f;

    for (int k = 0; k < K; k += 16) {
        const int kk = k + l5 * 8;
        short8 af[NA];
        af[0] = *(const short8*)(A0 + (size_t)mrow * K + kk);
        af[1] = *(const short8*)(A1 + (size_t)mrow * K + kk);
        if (NA > 2) af[2] = *(const short8*)(A2 + (size_t)mrow * K + kk);
        const unsigned short* wp = Wc + (size_t)nrow * K + kk;
        short8 w0 = *(const short8*)(wp);
        short8 w1 = *(const short8*)(wp + NK);
        if (NT == 6) {
            short8 w2 = *(const short8*)(wp + 2 * NK);
            o = mfma32(w0, af[2], o);
            o = mfma32(w1, af[1], o);
            o = mfma32(w2, af[0], o);
            o = mfma32(w0, af[1], o);
            o = mfma32(w1, af[0], o);
            o = mfma32(w0, af[0], o);
        } else {
            o = mfma32(w0, af[1], o);
            o = mfma32(w1, af[0], o);
            o = mfma32(w0, af[0], o);
        }
    }

    // epilogue: D[n][m]: col = l31 = m, row reg-mapped = n
    #pragma unroll
    for (int g = 0; g < 4; ++g) {
        const int nb = n0 + g * 8 + l5 * 4;
        const float4 b4 = *(const float4*)(bias + nb);
        float v0 = o[4 * g + 0] + b4.x;
        float v1 = o[4 * g + 1] + b4.y;
        float v2 = o[4 * g + 2] + b4.z;
        float v3 = o[4 * g + 3] + b4.w;
        if (!SOUT) {
            float4 st = {v0, v1, v2, v3};
            *(float4*)(Cf + (size_t)mrow * Nn + nb) = st;
        } else {
            unsigned short h0, h1, p0, p1, q0, q1, r0, r1;
            split2(v0, h0, h1); split2(v1, p0, p1);
            split2(v2, q0, q1); split2(v3, r0, r1);
            short4v s0 = {(short)h0, (short)p0, (short)q0, (short)r0};
            short4v s1 = {(short)h1, (short)p1, (short)q1, (short)r1};
            *(short4v*)(C0 + (size_t)mrow * Nn + nb) = s0;
            *(short4v*)(C1 + (size_t)mrow * Nn + nb) = s1;
        }
    }
}

// ---------------- pre-pass: split K (3 bf16 comps), V (1 comp, transposed)
// Kc: [head][n][64] bf16, 16B-chunk j stored at j ^ (n&7).
// Vt: [head][64 d][8192 n] bf16; within each 32-n group, 16B chunk c stored at c ^ (d&3).
__global__ __launch_bounds__(256) void split_kernel(
    const float* __restrict__ qkv,
    unsigned short* __restrict__ Kc0, unsigned short* __restrict__ Kc1,
    unsigned short* __restrict__ Kc2, unsigned short* __restrict__ Vt0)
{
    __shared__ unsigned short vts[64 * 80];
    const int h  = blockIdx.y;
    const int n0 = blockIdx.x * 64;
    const int t  = threadIdx.x;
    const int r  = t >> 2;
    const int n  = n0 + r;
    const int dc = (t & 3) * 16;

    {
        const float* kp = qkv + (size_t)n * 768 + 256 + h * 64 + dc;
        float kv[16];
        #pragma unroll
        for (int i = 0; i < 16; i += 4) {
            float4 f = *(const float4*)(kp + i);
            kv[i] = f.x; kv[i+1] = f.y; kv[i+2] = f.z; kv[i+3] = f.w;
        }
        #pragma unroll
        for (int half = 0; half < 2; ++half) {
            short8 c0, c1, c2;
            #pragma unroll
            for (int j = 0; j < 8; ++j) {
                unsigned short a, b, c;
                split3(kv[half * 8 + j], a, b, c);
                c0[j] = (short)a; c1[j] = (short)b; c2[j] = (short)c;
            }
            const int pos = ((dc >> 3) + half) ^ (n & 7);
            const size_t base = ((size_t)(h * 8192 + n)) * 64 + pos * 8;
            *(short8*)(Kc0 + base) = c0;
            *(short8*)(Kc1 + base) = c1;
            *(short8*)(Kc2 + base) = c2;
        }
    }
    {
        const float* vp = qkv + (size_t)n * 768 + 512 + h * 64 + dc;
        #pragma unroll
        for (int i = 0; i < 16; i += 4) {
            float4 f = *(const float4*)(vp + i);
            float vv[4] = {f.x, f.y, f.z, f.w};
            #pragma unroll
            for (int k2 = 0; k2 < 4; ++k2)
                vts[(dc + i + k2) * 80 + r] = f2bf(vv[k2]);
        }
    }
    __syncthreads();
    #pragma unroll
    for (int i = 0; i < 2; ++i) {
        const int q = t * 2 + i;            // 0..511: d(64) x nc(8)
        const int d = q >> 3, nc = q & 7;
        const int g = nc >> 2, c = nc & 3;
        short8 vv = *(const short8*)(&vts[d * 80 + nc * 8]);
        const size_t dst = ((size_t)(h * 64 + d)) * 8192 + n0 + g * 32 + ((c ^ (d & 3)) * 8);
        *(short8*)(Vt0 + dst) = vv;
    }
}

// ---------------- MFMA flash attention: 128 q/block, 32-key tiles, split-K x4 ----------------
// grid (64, 4 heads, 4 quarters) = 1024 blocks = exactly 4/CU; LDS 32KB (2 x 16KB dbuf).
__global__ __launch_bounds__(256, 4) void attn_mfma_kernel(
    const float* __restrict__ qkv,
    const unsigned short* __restrict__ Kc0, const unsigned short* __restrict__ Kc1,
    const unsigned short* __restrict__ Kc2, const unsigned short* __restrict__ Vt0,
    unsigned short* __restrict__ Op16, float* __restrict__ Ml)
{
    __shared__ __align__(16) char smem[32768];
    const int h    = blockIdx.y;
    const int quar = blockIdx.z;
    const int n0   = blockIdx.x * 128;
    const int t    = threadIdx.x;
    const int wv   = t >> 6;
    const int lane = t & 63;
    const int l31  = lane & 31, l5 = lane >> 5;
    const int qbase = n0 + wv * 32;

    // Q load + 3-way split (scale folds 1/8 and log2e)
    const float QSC = 0.125f * 1.4426950408889634f;
    short8 qf[3][4];
    #pragma unroll
    for (int ks = 0; ks < 4; ++ks) {
        const float* qp = qkv + (size_t)(qbase + l31) * 768 + h * 64 + ks * 16 + l5 * 8;
        float4 qa = *(const float4*)qp, qb4 = *(const float4*)(qp + 4);
        float qv[8] = {qa.x, qa.y, qa.z, qa.w, qb4.x, qb4.y, qb4.z, qb4.w};
        #pragma unroll
        for (int j = 0; j < 8; ++j) {
            unsigned short a, b, c;
            split3(qv[j] * QSC, a, b, c);
            qf[0][ks][j] = (short)a;
            qf[1][ks][j] = (short)b;
            qf[2][ks][j] = (short)c;
        }
    }

    // hoisted LDS read offsets (loop-invariant)
    int koff[4], voff[2][2];
    #pragma unroll
    for (int ks = 0; ks < 4; ++ks)
        koff[ks] = l31 * 128 + (((ks * 2 + l5) ^ (l31 & 7)) * 16);
    #pragma unroll
    for (int ks = 0; ks < 2; ++ks)
        #pragma unroll
        for (int db = 0; db < 2; ++db) {
            const int d = db * 32 + l31;
            voff[ks][db] = 12288 + d * 64 + (((ks * 2 + l5) ^ (d & 3)) * 16);
        }

    // staging: 16 x 1KB segs; wave wv owns segs wv*4..wv*4+3
    const char* sgb[4];
    int ldso[4];
    #pragma unroll
    for (int i = 0; i < 4; ++i) {
        const int s = wv * 4 + i;
        if (s < 12) {
            const int c = s >> 2, rb = s & 3;
            const unsigned short* base = (c == 0) ? Kc0 : (c == 1) ? Kc1 : Kc2;
            const int row = rb * 8 + (lane >> 3);
            sgb[i] = (const char*)(base + ((size_t)(h * 8192 + quar * 2048 + row)) * 64 + (lane & 7) * 8);
            ldso[i] = c * 4096 + rb * 1024;
        } else {
            const int v = s - 12;
            const int d = v * 16 + (lane >> 2);
            sgb[i] = (const char*)(Vt0 + ((size_t)(h * 64 + d)) * 8192 + quar * 2048 + (lane & 3) * 8);
            ldso[i] = 12288 + v * 1024;
        }
    }
    const size_t ktstride = (wv < 3) ? 4096 : 64;

    auto STAGE = [&](int kt, int bb) {
        #pragma unroll
        for (int i = 0; i < 4; ++i)
            gll16(sgb[i] + (size_t)kt * ktstride, &smem[bb * 16384 + ldso[i]]);
    };

    f32x16 o[2];
    #pragma unroll
    for (int db = 0; db < 2; ++db)
        #pragma unroll
        for (int r = 0; r < 16; ++r) o[db][r] = 0.f;
    float mr = -FLT_MAX, ls = 0.f;

    STAGE(0, 0);
    __syncthreads();

    for (int kt = 0; kt < 64; ++kt) {
        const int bb = kt & 1;
        if (kt < 63) STAGE(kt + 1, bb ^ 1);
        const char* buf = &smem[bb * 16384];

        // ---- QK^T (S^T[key][q]); 6-term split
        f32x16 s;
        #pragma unroll
        for (int r = 0; r < 16; ++r) s[r] = 0.f;

        __builtin_amdgcn_s_setprio(1);
        #pragma unroll
        for (int ks = 0; ks < 4; ++ks) {
            const int off = koff[ks];
            short8 k0 = *(const short8*)(buf + off);
            short8 k1 = *(const short8*)(buf + 4096 + off);
            short8 k2 = *(const short8*)(buf + 8192 + off);
            s = mfma32(k0, qf[2][ks], s);
            s = mfma32(k1, qf[1][ks], s);
            s = mfma32(k2, qf[0][ks], s);
            s = mfma32(k0, qf[1][ks], s);
            s = mfma32(k1, qf[0][ks], s);
            s = mfma32(k0, qf[0][ks], s);
        }
        __builtin_amdgcn_s_setprio(0);

        // ---- online softmax (exp2 domain), defer-max THR=12
        float mx = s[0];
        #pragma unroll
        for (int r = 1; r < 16; ++r) mx = fmaxf(mx, s[r]);
        mx = fmaxf(mx, __shfl_xor(mx, 32));
        if (__any(mx > mr + 12.0f)) {
            const float mn = fmaxf(mr, mx);
            const float alpha = exp2f(mr - mn);
            mr = mn;
            ls *= alpha;
            o[0] *= alpha;
            o[1] *= alpha;
        }
        float ps = 0.f;
        #pragma unroll
        for (int r = 0; r < 16; ++r) {
            float p = exp2f(s[r] - mr);
            s[r] = p;
            ps += p;
        }
        ps += __shfl_xor(ps, 32);
        ls += ps;

        // pack P to B-frags
        short8 pb[2];
        #pragma unroll
        for (int ks = 0; ks < 2; ++ks) {
            const int rb = ks * 8;
            unsigned int A0 = cvtpk(s[rb + 0], s[rb + 1]);
            unsigned int A1 = cvtpk(s[rb + 2], s[rb + 3]);
            unsigned int B0 = cvtpk(s[rb + 4], s[rb + 5]);
            unsigned int B1 = cvtpk(s[rb + 6], s[rb + 7]);
            plswap(A0, B0);
            plswap(A1, B1);
            u32x4 pw; pw[0] = A0; pw[1] = A1; pw[2] = B0; pw[3] = B1;
            pb[ks] = __builtin_bit_cast(short8, pw);
        }

        // ---- PV
        __builtin_amdgcn_s_setprio(1);
        #pragma unroll
        for (int ks = 0; ks < 2; ++ks) {
            #pragma unroll
            for (int db = 0; db < 2; ++db) {
                short8 v = *(const short8*)(buf + voff[ks][db]);
                o[db] = mfma32(v, pb[ks], o[db]);
            }
        }
        __builtin_amdgcn_s_setprio(0);

        __syncthreads();
    }

    // ---- epilogue
    {
        const int q = qbase + l31;
        unsigned short* opq = Op16 + ((size_t)((quar * 4 + h) * 8192 + q)) * 64;
        #pragma unroll
        for (int db = 0; db < 2; ++db) {
            #pragma unroll
            for (int tq = 0; tq < 4; ++tq) {
                const int d0 = db * 32 + tq * 8 + l5 * 4;
                unsigned int w0 = cvtpk(o[db][4 * tq + 0], o[db][4 * tq + 1]);
                unsigned int w1 = cvtpk(o[db][4 * tq + 2], o[db][4 * tq + 3]);
                uint2 st = {w0, w1};
                *(uint2*)(opq + d0) = st;
            }
        }
        if (l5 == 0) {
            Ml[((size_t)(quar * 4 + h) * 2 + 0) * 8192 + q] = mr;
            Ml[((size_t)(quar * 4 + h) * 2 + 1) * 8192 + q] = ls;
        }
    }
}

// ---------------- split-K combine over 4 partials -> aO split-2 bf16 ----------------
__global__ __launch_bounds__(256) void combine_kernel(
    const unsigned short* __restrict__ Op16, const float* __restrict__ Ml,
    unsigned short* __restrict__ aO0, unsigned short* __restrict__ aO1)
{
    const int idx = blockIdx.x * 256 + threadIdx.x;
    const int c = idx & 3;
    const int q = (idx >> 2) & 8191;
    const int h = idx >> 15;
    float m[4], l[4];
    float mg = -FLT_MAX;
    #pragma unroll
    for (int s = 0; s < 4; ++s) {
        m[s] = Ml[((size_t)(s * 4 + h) * 2 + 0) * 8192 + q];
        l[s] = Ml[((size_t)(s * 4 + h) * 2 + 1) * 8192 + q];
        mg = fmaxf(mg, m[s]);
    }
    float w[4], denom = 0.f;
    #pragma unroll
    for (int s = 0; s < 4; ++s) {
        w[s] = exp2f(m[s] - mg);
        denom += l[s] * w[s];
    }
    const float inv = 1.f / denom;
    float acc[16] = {};
    #pragma unroll
    for (int s = 0; s < 4; ++s) {
        const unsigned short* p = Op16 + ((size_t)(s * 4 + h) * 8192 + q) * 64 + c * 16;
        short8 v0 = *(const short8*)(p);
        short8 v1 = *(const short8*)(p + 8);
        #pragma unroll
        for (int i = 0; i < 8; ++i) {
            acc[i]     += w[s] * bf2f((unsigned short)v0[i]);
            acc[i + 8] += w[s] * bf2f((unsigned short)v1[i]);
        }
    }
    unsigned short* d0 = aO0 + (size_t)q * 256 + h * 64 + c * 16;
    unsigned short* d1 = aO1 + (size_t)q * 256 + h * 64 + c * 16;
    short8 o0, o1;
    #pragma unroll
    for (int i = 0; i < 8; ++i) {
        unsigned short a, b;
        split2(acc[i] * inv, a, b);
        o0[i] = (short)a; o1[i] = (short)b;
    }
    *(short8*)(d0) = o0;
    *(short8*)(d1) = o1;
    #pragma unroll
    for (int i = 0; i < 8; ++i) {
        unsigned short a, b;
        split2(acc[i + 8] * inv, a, b);
        o0[i] = (short)a; o1[i] = (short)b;
    }
    *(short8*)(d0 + 8) = o0;
    *(short8*)(d1 + 8) = o1;
}

// ---------------- launch ----------------
extern "C" void kernel_launch(void* const* d_in, const int* in_sizes, int n_in,
                              void* d_out, int out_size, void* d_ws, size_t ws_size,
                              hipStream_t stream)
{
    const float* x     = (const float*)d_in[0];
    const int*   ei    = (const int*)  d_in[1];
    const float* W_in  = (const float*)d_in[2];
    const float* b_in  = (const float*)d_in[3];
    const float* plas  = (const float*)d_in[4];
    const float* syn   = (const float*)d_in[5];
    const float* inpw  = (const float*)d_in[6];
    const float* inpb  = (const float*)d_in[7];
    const float* outpw = (const float*)d_in[8];
    const float* outpb = (const float*)d_in[9];
    const float* Wout  = (const float*)d_in[10];
    const float* bout  = (const float*)d_in[11];
    float* out = (float*)d_out;

    char* ws = (char*)d_ws;
    // layout (58.1 MiB):
    //  0..8MB   : h fp32 (GNN) -> Kc0@0,Kc1@4 (attn) -> aOc0@0,aOc1@4 (post)
    //  8..16MB  : h2 fp32 (L0/L1) -> h2c0@8,h2c1@12 (L2 out) -> Kc2@8,Vt0@12 -> tmpc0@8,tmpc1@12
    // 16..40MB  : xc0@16,xc1@18,xc2@20 (pre) -> qkv fp32 (live through attn) -> opc@16,woc@17 (post)
    // 40..56MB  : h2c2@40, Wic@44, ipc@45 (pre-attn) -> Op16 (16MB, attn)
    // 56MB..    : rowp, curs, esrc (-> Ml during attn)
    float* h    = (float*)(ws + 0);
    float* h2   = (float*)(ws + (8u  << 20));
    float* qkv  = (float*)(ws + (16u << 20));
    unsigned short* xc0  = (unsigned short*)(ws + (16u << 20));
    unsigned short* xc1  = (unsigned short*)(ws + (18u << 20));
    unsigned short* xc2  = (unsigned short*)(ws + (20u << 20));
    unsigned short* h2c0 = (unsigned short*)(ws + (8u  << 20));
    unsigned short* h2c1 = (unsigned short*)(ws + (12u << 20));
    unsigned short* h2c2 = (unsigned short*)(ws + (40u << 20));
    unsigned short* Wic  = (unsigned short*)(ws + (44u << 20));   // W_in comps, 192KB
    unsigned short* ipc  = (unsigned short*)(ws + (45u << 20));   // inpw comps, 1.15MB
    unsigned short* opc  = (unsigned short*)(ws + (16u << 20));   // outpw comps (post-attn)
    unsigned short* woc  = (unsigned short*)(ws + (17u << 20));   // Wout comps (post-attn)
    unsigned short* Kc0  = (unsigned short*)(ws + 0);
    unsigned short* Kc1  = (unsigned short*)(ws + (4u  << 20));
    unsigned short* Kc2  = (unsigned short*)(ws + (8u  << 20));
    unsigned short* Vt0  = (unsigned short*)(ws + (12u << 20));
    unsigned short* Op16 = (unsigned short*)(ws + (40u << 20));
    unsigned short* aOc0 = (unsigned short*)(ws + 0);
    unsigned short* aOc1 = (unsigned short*)(ws + (4u  << 20));
    unsigned short* tmpc0 = (unsigned short*)(ws + (8u  << 20));
    unsigned short* tmpc1 = (unsigned short*)(ws + (12u << 20));
    int*   rowp = (int*)(ws + (56u << 20));
    int*   curs = (int*)(ws + (56u << 20) + 40960);
    int*   esrc = (int*)(ws + (56u << 20) + 81920);
    float* Ml   = (float*)(ws + (56u << 20) + 81920);

    // CSR build
    hipMemsetAsync(curs, 0, N_NODES * sizeof(int), stream);
    hist_kernel<<<NEDGE / 256, 256, 0, stream>>>(ei, curs);
    scan_kernel<<<1, 1024, 0, stream>>>(curs, rowp, curs);
    scatter_kernel<<<NEDGE / 256, 256, 0, stream>>>(ei, curs, esrc);

    // pre-split inputs & pre-attn weights
    split_w_kernel<<<(HID * IND) / 2048, 256, 0, stream>>>(W_in, Wic, HID * IND);
    split_w_kernel<<<(768 * HID) / 2048, 256, 0, stream>>>(inpw, ipc, 768 * HID);
    split_w_kernel<<<(N_NODES * IND) / 2048, 256, 0, stream>>>(x, xc0, N_NODES * IND);
    // note: split_w with comp stride; for x we reuse it (xc0/xc1/xc2 contiguous 2MB apart)

    // in-proj (6-term MFMA): h = x @ W_in^T + b_in
    mfma_gemm_kernel<6, 3, false><<<dim3(N_NODES / 64, HID / 64), 256, 0, stream>>>(
        xc0, xc0 + N_NODES * IND, xc0 + 2 * N_NODES * IND, Wic, b_in,
        h, nullptr, nullptr, N_NODES, HID, IND);

    // 3 GNN layers (XCD-affine column-sliced; last layer emits split-3 bf16)
    aggregate_sliced_kernel<<<N_NODES, 256, 0, stream>>>(h,  h2, rowp, esrc, plas, syn, 0);
    aggregate_sliced_kernel<<<N_NODES, 256, 0, stream>>>(h2, h,  rowp, esrc, plas, syn, 1);
    aggregate_sliced_split_kernel<<<N_NODES, 256, 0, stream>>>(h, h2c0, h2c1, h2c2,
                                                               rowp, esrc, plas, syn, 2);

    // qkv projection (6-term MFMA)
    mfma_gemm_kernel<6, 3, false><<<dim3(N_NODES / 64, 768 / 64), 256, 0, stream>>>(
        h2c0, h2c1, h2c2, ipc, inpb, qkv, nullptr, nullptr, N_NODES, 768, HID);

    // split pre-pass (K 3-comp, V transposed)
    split_kernel<<<dim3(N_NODES / 64, NHEAD), 256, 0, stream>>>(
        qkv, Kc0, Kc1, Kc2, Vt0);

    // MFMA attention: 128 q/block, 32-key tiles, split-K x4 (1024 blocks)
    attn_mfma_kernel<<<dim3(N_NODES / 128, NHEAD, 4), 256, 0, stream>>>(
        qkv, Kc0, Kc1, Kc2, Vt0, Op16, Ml);

    // combine quarters -> aO (split-2 bf16)
    combine_kernel<<<512, 256, 0, stream>>>(Op16, Ml, aOc0, aOc1);

    // post-attn weight splits (qkv region now dead)
    split_w_kernel<<<(HID * HID) / 2048, 256, 0, stream>>>(outpw, opc, HID * HID);
    split_w_kernel<<<(OUTD * HID) / 2048, 256, 0, stream>>>(Wout, woc, OUTD * HID);

    // output projections (3-term MFMA)
    mfma_gemm_kernel<3, 2, true><<<dim3(N_NODES / 64, HID / 64), 256, 0, stream>>>(
        aOc0, aOc1, nullptr, opc, outpb, nullptr, tmpc0, tmpc1, N_NODES, HID, HID);
    mfma_gemm_kernel<3, 2, false><<<dim3(N_NODES / 64, OUTD / 64), 256, 0, stream>>>(
        tmpc0, tmpc1, nullptr, woc, bout, out, nullptr, nullptr, N_NODES, OUTD, HID);
}

// Round 8
// 569.627 us; speedup vs baseline: 1.0763x; 1.0763x over previous
//
#include <hip/hip_runtime.h>
#include <hip/hip_bf16.h>
#include <float.h>

#define N_NODES 8192
#define NEDGE   524288
#define IND     128
#define HID     256
#define OUTD    128
#define NHEAD   4
#define HD      64

typedef short short8 __attribute__((ext_vector_type(8)));
typedef short short4v __attribute__((ext_vector_type(4)));
typedef float f32x4  __attribute__((ext_vector_type(4)));
typedef float f32x16 __attribute__((ext_vector_type(16)));
typedef unsigned int u32x4 __attribute__((ext_vector_type(4)));

__device__ __forceinline__ float sigmoidf_(float x) { return 1.0f / (1.0f + expf(-x)); }

__device__ __forceinline__ unsigned short f2bf(float f) {
    __hip_bfloat16 b = __float2bfloat16(f);
    return __builtin_bit_cast(unsigned short, b);
}
__device__ __forceinline__ float bf2f(unsigned short u) {
    __hip_bfloat16 b = __builtin_bit_cast(__hip_bfloat16, u);
    return __bfloat162float(b);
}
__device__ __forceinline__ void split3(float x, unsigned short& a, unsigned short& b, unsigned short& c) {
    a = f2bf(x); float r = x - bf2f(a);
    b = f2bf(r); r = r - bf2f(b);
    c = f2bf(r);
}
__device__ __forceinline__ void split2(float x, unsigned short& a, unsigned short& b) {
    a = f2bf(x); float r = x - bf2f(a);
    b = f2bf(r);
}
__device__ __forceinline__ unsigned int cvtpk(float lo, float hi) {
    unsigned int r;
    asm("v_cvt_pk_bf16_f32 %0, %1, %2" : "=v"(r) : "v"(lo), "v"(hi));
    return r;
}
__device__ __forceinline__ void plswap(unsigned int& a, unsigned int& b) {
    asm volatile("v_permlane32_swap_b32 %0, %1" : "+v"(a), "+v"(b));
}
__device__ __forceinline__ void gll16(const void* g, void* l) {
    __builtin_amdgcn_global_load_lds(
        (const __attribute__((address_space(1))) void*)g,
        (__attribute__((address_space(3))) void*)l, 16, 0, 0);
}
__device__ __forceinline__ f32x16 mfma32(short8 a, short8 b, f32x16 c) {
    return __builtin_amdgcn_mfma_f32_32x32x16_bf16(a, b, c, 0, 0, 0);
}

// ---------------- CSR build ----------------
__global__ void hist_kernel(const int* __restrict__ ei, int* __restrict__ deg)
{
    int e = blockIdx.x * blockDim.x + threadIdx.x;
    if (e < NEDGE) atomicAdd(&deg[ei[NEDGE + e]], 1);
}

__global__ __launch_bounds__(1024) void scan_kernel(
    const int* __restrict__ deg, int* __restrict__ row_ptr, int* __restrict__ cursor)
{
    __shared__ int sh[1024];
    const int t = threadIdx.x;
    int v[8]; int s = 0;
    #pragma unroll
    for (int i = 0; i < 8; ++i) { v[i] = deg[t * 8 + i]; s += v[i]; }
    sh[t] = s; __syncthreads();
    for (int off = 1; off < 1024; off <<= 1) {
        int add = (t >= off) ? sh[t - off] : 0;
        __syncthreads();
        sh[t] += add;
        __syncthreads();
    }
    int base = sh[t] - s;
    #pragma unroll
    for (int i = 0; i < 8; ++i) {
        row_ptr[t * 8 + i] = base;
        cursor[t * 8 + i]  = base;
        base += v[i];
    }
    if (t == 1023) row_ptr[N_NODES] = base;
}

__global__ void scatter_kernel(const int* __restrict__ ei, int* __restrict__ cursor,
                               int* __restrict__ esrc)
{
    int e = blockIdx.x * blockDim.x + threadIdx.x;
    if (e < NEDGE) {
        int d = ei[NEDGE + e];
        int p = atomicAdd(&cursor[d], 1);
        esrc[p] = ei[e];
    }
}

// ---------------- split fp32 array -> 3 bf16 comps (comp stride = elems) ----------------
__global__ __launch_bounds__(256) void split_w_kernel(
    const float* __restrict__ w, unsigned short* __restrict__ Wc, int elems)
{
    const int i = (blockIdx.x * 256 + threadIdx.x) * 8;
    if (i >= elems) return;
    float4 a = *(const float4*)(w + i);
    float4 b = *(const float4*)(w + i + 4);
    float v[8] = {a.x, a.y, a.z, a.w, b.x, b.y, b.z, b.w};
    short8 c0, c1, c2;
    #pragma unroll
    for (int j = 0; j < 8; ++j) {
        unsigned short p, q, r;
        split3(v[j], p, q, r);
        c0[j] = (short)p; c1[j] = (short)q; c2[j] = (short)r;
    }
    *(short8*)(Wc + i) = c0;
    *(short8*)(Wc + elems + i) = c1;
    *(short8*)(Wc + 2 * elems + i) = c2;
}

// ---------------- GNN aggregate: float4 gathers, 16-lane groups, 4 col-slices ----------------
// grid 2048 blocks: slice = b&3 (64 cols), 16 dst-nodes/block (one per 16-lane group).
// SPLIT=1: emit split-3 bf16 (last layer).
template<int SPLIT>
__global__ __launch_bounds__(256) void aggregate4_kernel(
    const float* __restrict__ hin, float* __restrict__ hout,
    unsigned short* __restrict__ H0, unsigned short* __restrict__ H1,
    unsigned short* __restrict__ H2,
    const int* __restrict__ row_ptr, const int* __restrict__ esrc,
    const float* __restrict__ plas, const float* __restrict__ syn, int layer)
{
    const int b = blockIdx.x;
    const int slice = b & 3, gb = b >> 2;
    const int t = threadIdx.x;
    const int g = t >> 4;            // 0..15 dst group
    const int c4 = (t & 15) * 4;     // col within slice
    const int dst = gb * 16 + g;
    const int col = slice * 64 + c4;
    const int st = row_ptr[dst], en = row_ptr[dst + 1];

    float a0x=0,a0y=0,a0z=0,a0w=0, a1x=0,a1y=0,a1z=0,a1w=0;
    float a2x=0,a2y=0,a2z=0,a2w=0, a3x=0,a3y=0,a3z=0,a3w=0;
    int e = st;
    for (; e + 4 <= en; e += 4) {
        int s0 = esrc[e], s1 = esrc[e + 1], s2 = esrc[e + 2], s3 = esrc[e + 3];
        float4 v0 = *(const float4*)(hin + (size_t)s0 * HID + col);
        float4 v1 = *(const float4*)(hin + (size_t)s1 * HID + col);
        float4 v2 = *(const float4*)(hin + (size_t)s2 * HID + col);
        float4 v3 = *(const float4*)(hin + (size_t)s3 * HID + col);
        a0x += v0.x; a0y += v0.y; a0z += v0.z; a0w += v0.w;
        a1x += v1.x; a1y += v1.y; a1z += v1.z; a1w += v1.w;
        a2x += v2.x; a2y += v2.y; a2z += v2.z; a2w += v2.w;
        a3x += v3.x; a3y += v3.y; a3z += v3.z; a3w += v3.w;
    }
    float rx = (a0x + a1x) + (a2x + a3x);
    float ry = (a0y + a1y) + (a2y + a3y);
    float rz = (a0z + a1z) + (a2z + a3z);
    float rw = (a0w + a1w) + (a2w + a3w);
    for (; e < en; ++e) {
        float4 v = *(const float4*)(hin + (size_t)esrc[e] * HID + col);
        rx += v.x; ry += v.y; rz += v.z; rw += v.w;
    }
    const float scale = sigmoidf_(plas[layer]) * sigmoidf_(syn[layer]);
    float o4[4] = {rx * scale, ry * scale, rz * scale, rw * scale};
    #pragma unroll
    for (int i = 0; i < 4; ++i) o4[i] = (o4[i] > 0.f) ? o4[i] : 0.01f * o4[i];

    if (SPLIT == 0) {
        float4 stv = {o4[0], o4[1], o4[2], o4[3]};
        *(float4*)(hout + (size_t)dst * HID + col) = stv;
    } else {
        short4v h0, h1, h2;
        #pragma unroll
        for (int i = 0; i < 4; ++i) {
            unsigned short p, q, r;
            split3(o4[i], p, q, r);
            h0[i] = (short)p; h1[i] = (short)q; h2[i] = (short)r;
        }
        *(short4v*)(H0 + (size_t)dst * HID + col) = h0;
        *(short4v*)(H1 + (size_t)dst * HID + col) = h1;
        *(short4v*)(H2 + (size_t)dst * HID + col) = h2;
    }
}

// ---------------- MFMA split-precision GEMM (pre-split A and W) ----------------
template<int NT, int NA, bool SOUT>
__global__ __launch_bounds__(256) void mfma_gemm_kernel(
    const unsigned short* __restrict__ A0, const unsigned short* __restrict__ A1,
    const unsigned short* __restrict__ A2,
    const unsigned short* __restrict__ Wc, const float* __restrict__ bias,
    float* __restrict__ Cf, unsigned short* __restrict__ C0, unsigned short* __restrict__ C1,
    int M, int Nn, int K)
{
    const int t = threadIdx.x;
    const int wv = t >> 6, lane = t & 63;
    const int l31 = lane & 31, l5 = lane >> 5;
    const int wm = wv & 1, wn = wv >> 1;
    const int m0 = blockIdx.x * 64 + wm * 32;
    const int n0 = blockIdx.y * 64 + wn * 32;
    const int mrow = m0 + l31;
    const int nrow = n0 + l31;
    const size_t NK = (size_t)Nn * K;

    f32x16 o;
    #pragma unroll
    for (int r = 0; r < 16; ++r) o[r] = 0.f;

    for (int k = 0; k < K; k += 16) {
        const int kk = k + l5 * 8;
        short8 af[NA];
        af[0] = *(const short8*)(A0 + (size_t)mrow * K + kk);
        af[1] = *(const short8*)(A1 + (size_t)mrow * K + kk);
        if (NA > 2) af[2] = *(const short8*)(A2 + (size_t)mrow * K + kk);
        const unsigned short* wp = Wc + (size_t)nrow * K + kk;
        short8 w0 = *(const short8*)(wp);
        short8 w1 = *(const short8*)(wp + NK);
        if (NT == 6) {
            short8 w2 = *(const short8*)(wp + 2 * NK);
            o = mfma32(w0, af[2], o);
            o = mfma32(w1, af[1], o);
            o = mfma32(w2, af[0], o);
            o = mfma32(w0, af[1], o);
            o = mfma32(w1, af[0], o);
            o = mfma32(w0, af[0], o);
        } else {
            o = mfma32(w0, af[1], o);
            o = mfma32(w1, af[0], o);
            o = mfma32(w0, af[0], o);
        }
    }

    #pragma unroll
    for (int g = 0; g < 4; ++g) {
        const int nb = n0 + g * 8 + l5 * 4;
        const float4 b4 = *(const float4*)(bias + nb);
        float v0 = o[4 * g + 0] + b4.x;
        float v1 = o[4 * g + 1] + b4.y;
        float v2 = o[4 * g + 2] + b4.z;
        float v3 = o[4 * g + 3] + b4.w;
        if (!SOUT) {
            float4 stv = {v0, v1, v2, v3};
            *(float4*)(Cf + (size_t)mrow * Nn + nb) = stv;
        } else {
            unsigned short h0, h1, p0, p1, q0, q1, r0, r1;
            split2(v0, h0, h1); split2(v1, p0, p1);
            split2(v2, q0, q1); split2(v3, r0, r1);
            short4v s0 = {(short)h0, (short)p0, (short)q0, (short)r0};
            short4v s1 = {(short)h1, (short)p1, (short)q1, (short)r1};
            *(short4v*)(C0 + (size_t)mrow * Nn + nb) = s0;
            *(short4v*)(C1 + (size_t)mrow * Nn + nb) = s1;
        }
    }
}

// ---------------- pre-pass: split K (3 bf16 comps), V (1 comp, transposed)
// Kc: [head][n][64] bf16, 16B-chunk j stored at j ^ (n&7).
// Vt: [head][64 d][8192 n] bf16; within each 32-n group, 16B chunk c stored at c ^ (d&3).
__global__ __launch_bounds__(256) void split_kernel(
    const float* __restrict__ qkv,
    unsigned short* __restrict__ Kc0, unsigned short* __restrict__ Kc1,
    unsigned short* __restrict__ Kc2, unsigned short* __restrict__ Vt0)
{
    __shared__ unsigned short vts[64 * 80];
    const int h  = blockIdx.y;
    const int n0 = blockIdx.x * 64;
    const int t  = threadIdx.x;
    const int r  = t >> 2;
    const int n  = n0 + r;
    const int dc = (t & 3) * 16;

    {
        const float* kp = qkv + (size_t)n * 768 + 256 + h * 64 + dc;
        float kv[16];
        #pragma unroll
        for (int i = 0; i < 16; i += 4) {
            float4 f = *(const float4*)(kp + i);
            kv[i] = f.x; kv[i+1] = f.y; kv[i+2] = f.z; kv[i+3] = f.w;
        }
        #pragma unroll
        for (int half = 0; half < 2; ++half) {
            short8 c0, c1, c2;
            #pragma unroll
            for (int j = 0; j < 8; ++j) {
                unsigned short a, b, c;
                split3(kv[half * 8 + j], a, b, c);
                c0[j] = (short)a; c1[j] = (short)b; c2[j] = (short)c;
            }
            const int pos = ((dc >> 3) + half) ^ (n & 7);
            const size_t base = ((size_t)(h * 8192 + n)) * 64 + pos * 8;
            *(short8*)(Kc0 + base) = c0;
            *(short8*)(Kc1 + base) = c1;
            *(short8*)(Kc2 + base) = c2;
        }
    }
    {
        const float* vp = qkv + (size_t)n * 768 + 512 + h * 64 + dc;
        #pragma unroll
        for (int i = 0; i < 16; i += 4) {
            float4 f = *(const float4*)(vp + i);
            float vv[4] = {f.x, f.y, f.z, f.w};
            #pragma unroll
            for (int k2 = 0; k2 < 4; ++k2)
                vts[(dc + i + k2) * 80 + r] = f2bf(vv[k2]);
        }
    }
    __syncthreads();
    #pragma unroll
    for (int i = 0; i < 2; ++i) {
        const int q = t * 2 + i;            // 0..511: d(64) x nc(8)
        const int d = q >> 3, nc = q & 7;
        const int g = nc >> 2, c = nc & 3;
        short8 vv = *(const short8*)(&vts[d * 80 + nc * 8]);
        const size_t dst = ((size_t)(h * 64 + d)) * 8192 + n0 + g * 32 + ((c ^ (d & 3)) * 8);
        *(short8*)(Vt0 + dst) = vv;
    }
}

// ---------------- pipelined MFMA flash attention ----------------
// 128 q/block (4 waves x 32q), 32-key tiles, split-K x2, TRIPLE-buffered LDS (3 x 16KB),
// counted vmcnt(4): staging 2 tiles ahead, never drains in steady state.
// Per iter: QK(kt+1) MFMA || softmax(kt) VALU, then PV(kt). Matrix-pipe-bound by design.
__global__ __launch_bounds__(256, 2) void attn_pipe_kernel(
    const float* __restrict__ qkv,
    const unsigned short* __restrict__ Kc0, const unsigned short* __restrict__ Kc1,
    const unsigned short* __restrict__ Kc2, const unsigned short* __restrict__ Vt0,
    unsigned short* __restrict__ Op16, float* __restrict__ Ml)
{
    __shared__ __align__(16) char smem[49152];
    const int h    = blockIdx.y;
    const int half = blockIdx.z;
    const int n0   = blockIdx.x * 128;
    const int t    = threadIdx.x;
    const int wv   = t >> 6;
    const int lane = t & 63;
    const int l31  = lane & 31, l5 = lane >> 5;
    const int qbase = n0 + wv * 32;

    // Q load + 3-way split (scale folds 1/8 and log2e)
    const float QSC = 0.125f * 1.4426950408889634f;
    short8 qf[3][4];
    #pragma unroll
    for (int ks = 0; ks < 4; ++ks) {
        const float* qp = qkv + (size_t)(qbase + l31) * 768 + h * 64 + ks * 16 + l5 * 8;
        float4 qa = *(const float4*)qp, qb4 = *(const float4*)(qp + 4);
        float qv[8] = {qa.x, qa.y, qa.z, qa.w, qb4.x, qb4.y, qb4.z, qb4.w};
        #pragma unroll
        for (int j = 0; j < 8; ++j) {
            unsigned short a, b, c;
            split3(qv[j] * QSC, a, b, c);
            qf[0][ks][j] = (short)a;
            qf[1][ks][j] = (short)b;
            qf[2][ks][j] = (short)c;
        }
    }

    // hoisted LDS read offsets
    int koff[4], voff[2][2];
    #pragma unroll
    for (int ks = 0; ks < 4; ++ks)
        koff[ks] = l31 * 128 + (((ks * 2 + l5) ^ (l31 & 7)) * 16);
    #pragma unroll
    for (int ks = 0; ks < 2; ++ks)
        #pragma unroll
        for (int db = 0; db < 2; ++db) {
            const int d = db * 32 + l31;
            voff[ks][db] = 12288 + d * 64 + (((ks * 2 + l5) ^ (d & 3)) * 16);
        }

    // staging: 16 x 1KB segs per tile; wave wv owns segs wv*4..wv*4+3 (4 gll insts/tile)
    const char* sgb[4];
    int ldso[4];
    #pragma unroll
    for (int i = 0; i < 4; ++i) {
        const int s = wv * 4 + i;
        if (s < 12) {
            const int c = s >> 2, rb = s & 3;
            const unsigned short* base = (c == 0) ? Kc0 : (c == 1) ? Kc1 : Kc2;
            const int row = rb * 8 + (lane >> 3);
            sgb[i] = (const char*)(base + ((size_t)(h * 8192 + half * 4096 + row)) * 64 + (lane & 7) * 8);
            ldso[i] = c * 4096 + rb * 1024;
        } else {
            const int v = s - 12;
            const int d = v * 16 + (lane >> 2);
            sgb[i] = (const char*)(Vt0 + ((size_t)(h * 64 + d)) * 8192 + half * 4096 + (lane & 3) * 8);
            ldso[i] = 12288 + v * 1024;
        }
    }
    const size_t ktstride = (wv < 3) ? 4096 : 64;

    auto STAGE = [&](int kt, int bo) {
        #pragma unroll
        for (int i = 0; i < 4; ++i)
            gll16(sgb[i] + (size_t)kt * ktstride, &smem[bo + ldso[i]]);
    };

    f32x16 o[2];
    #pragma unroll
    for (int db = 0; db < 2; ++db)
        #pragma unroll
        for (int r = 0; r < 16; ++r) o[db][r] = 0.f;
    float mr = -FLT_MAX, ls = 0.f;

    auto QK = [&](const char* buf, f32x16& sreg) {
        #pragma unroll
        for (int r = 0; r < 16; ++r) sreg[r] = 0.f;
        __builtin_amdgcn_s_setprio(1);
        #pragma unroll
        for (int ks = 0; ks < 4; ++ks) {
            short8 k0 = *(const short8*)(buf + koff[ks]);
            short8 k1 = *(const short8*)(buf + 4096 + koff[ks]);
            short8 k2 = *(const short8*)(buf + 8192 + koff[ks]);
            sreg = mfma32(k0, qf[2][ks], sreg);
            sreg = mfma32(k1, qf[1][ks], sreg);
            sreg = mfma32(k2, qf[0][ks], sreg);
            sreg = mfma32(k0, qf[1][ks], sreg);
            sreg = mfma32(k1, qf[0][ks], sreg);
            sreg = mfma32(k0, qf[0][ks], sreg);
        }
        __builtin_amdgcn_s_setprio(0);
    };

    int cb = 0, nb = 16384, fb = 32768;

    // ITER: stage kt+2 -> fb, wait tile kt+1, QK(kt+1)->snxt || SM(kt) on scur, PV(kt) from cb
    auto ITER = [&](int kt, f32x16& scur, f32x16& snxt) {
        const bool more = (kt + 2) < 128;
        if (more) {
            STAGE(kt + 2, fb);
            asm volatile("s_waitcnt vmcnt(4)" ::: "memory");
        } else {
            asm volatile("s_waitcnt vmcnt(0)" ::: "memory");
        }
        __builtin_amdgcn_s_barrier();
        __builtin_amdgcn_sched_barrier(0);

        if (kt + 1 < 128) QK(&smem[nb], snxt);   // MFMA, independent of SM below

        // softmax on scur (VALU; overlaps QK's matrix-pipe time)
        float mx = scur[0];
        #pragma unroll
        for (int r = 1; r < 16; ++r) mx = fmaxf(mx, scur[r]);
        mx = fmaxf(mx, __shfl_xor(mx, 32));
        if (__any(mx > mr + 12.0f)) {
            const float mn = fmaxf(mr, mx);
            const float al = exp2f(mr - mn);
            mr = mn; ls *= al;
            o[0] *= al; o[1] *= al;
        }
        float ps = 0.f;
        #pragma unroll
        for (int r = 0; r < 16; ++r) {
            float p = exp2f(scur[r] - mr);
            scur[r] = p;
            ps += p;
        }
        ps += __shfl_xor(ps, 32);
        ls += ps;

        short8 pb0, pb1;
        {
            unsigned int A0 = cvtpk(scur[0], scur[1]);
            unsigned int A1 = cvtpk(scur[2], scur[3]);
            unsigned int B0 = cvtpk(scur[4], scur[5]);
            unsigned int B1 = cvtpk(scur[6], scur[7]);
            plswap(A0, B0); plswap(A1, B1);
            u32x4 pw; pw[0] = A0; pw[1] = A1; pw[2] = B0; pw[3] = B1;
            pb0 = __builtin_bit_cast(short8, pw);
            unsigned int C0_ = cvtpk(scur[8],  scur[9]);
            unsigned int C1_ = cvtpk(scur[10], scur[11]);
            unsigned int D0 = cvtpk(scur[12], scur[13]);
            unsigned int D1 = cvtpk(scur[14], scur[15]);
            plswap(C0_, D0); plswap(C1_, D1);
            u32x4 pw2; pw2[0] = C0_; pw2[1] = C1_; pw2[2] = D0; pw2[3] = D1;
            pb1 = __builtin_bit_cast(short8, pw2);
        }

        // PV from current buffer
        __builtin_amdgcn_s_setprio(1);
        {
            const char* bufc = &smem[cb];
            short8 v00 = *(const short8*)(bufc + voff[0][0]);
            short8 v01 = *(const short8*)(bufc + voff[0][1]);
            o[0] = mfma32(v00, pb0, o[0]);
            o[1] = mfma32(v01, pb0, o[1]);
            short8 v10 = *(const short8*)(bufc + voff[1][0]);
            short8 v11 = *(const short8*)(bufc + voff[1][1]);
            o[0] = mfma32(v10, pb1, o[0]);
            o[1] = mfma32(v11, pb1, o[1]);
        }
        __builtin_amdgcn_s_setprio(0);

        __builtin_amdgcn_sched_barrier(0);
        __builtin_amdgcn_s_barrier();
        int tmp = cb; cb = nb; nb = fb; fb = tmp;   // rotate buffers
    };

    // prologue: stage tiles 0 and 1, compute QK(0)
    STAGE(0, 0);
    STAGE(1, 16384);
    asm volatile("s_waitcnt vmcnt(4)" ::: "memory");
    __builtin_amdgcn_s_barrier();
    __builtin_amdgcn_sched_barrier(0);
    f32x16 sA, sB;
    QK(&smem[0], sA);

    for (int kt = 0; kt < 128; kt += 2) {
        ITER(kt,     sA, sB);
        ITER(kt + 1, sB, sA);
    }

    // epilogue: unnormalized partial O (bf16) + m,l
    {
        const int q = qbase + l31;
        unsigned short* opq = Op16 + ((size_t)((half * 4 + h) * 8192 + q)) * 64;
        #pragma unroll
        for (int db = 0; db < 2; ++db) {
            #pragma unroll
            for (int tq = 0; tq < 4; ++tq) {
                const int d0 = db * 32 + tq * 8 + l5 * 4;
                unsigned int w0 = cvtpk(o[db][4 * tq + 0], o[db][4 * tq + 1]);
                unsigned int w1 = cvtpk(o[db][4 * tq + 2], o[db][4 * tq + 3]);
                uint2 stv = {w0, w1};
                *(uint2*)(opq + d0) = stv;
            }
        }
        if (l5 == 0) {
            Ml[((size_t)(half * 4 + h) * 2 + 0) * 8192 + q] = mr;
            Ml[((size_t)(half * 4 + h) * 2 + 1) * 8192 + q] = ls;
        }
    }
}

// ---------------- split-K combine over 2 partials -> aO split-2 bf16 ----------------
__global__ __launch_bounds__(256) void combine_kernel(
    const unsigned short* __restrict__ Op16, const float* __restrict__ Ml,
    unsigned short* __restrict__ aO0, unsigned short* __restrict__ aO1)
{
    const int idx = blockIdx.x * 256 + threadIdx.x;
    const int c = idx & 3;
    const int q = (idx >> 2) & 8191;
    const int h = idx >> 15;
    float m[2], l[2];
    #pragma unroll
    for (int s = 0; s < 2; ++s) {
        m[s] = Ml[((size_t)(s * 4 + h) * 2 + 0) * 8192 + q];
        l[s] = Ml[((size_t)(s * 4 + h) * 2 + 1) * 8192 + q];
    }
    const float mg = fmaxf(m[0], m[1]);
    float w[2];
    w[0] = exp2f(m[0] - mg);
    w[1] = exp2f(m[1] - mg);
    const float inv = 1.f / (l[0] * w[0] + l[1] * w[1]);
    float acc[16] = {};
    #pragma unroll
    for (int s = 0; s < 2; ++s) {
        const unsigned short* p = Op16 + ((size_t)(s * 4 + h) * 8192 + q) * 64 + c * 16;
        short8 v0 = *(const short8*)(p);
        short8 v1 = *(const short8*)(p + 8);
        #pragma unroll
        for (int i = 0; i < 8; ++i) {
            acc[i]     += w[s] * bf2f((unsigned short)v0[i]);
            acc[i + 8] += w[s] * bf2f((unsigned short)v1[i]);
        }
    }
    unsigned short* d0 = aO0 + (size_t)q * 256 + h * 64 + c * 16;
    unsigned short* d1 = aO1 + (size_t)q * 256 + h * 64 + c * 16;
    short8 o0, o1;
    #pragma unroll
    for (int i = 0; i < 8; ++i) {
        unsigned short a, b;
        split2(acc[i] * inv, a, b);
        o0[i] = (short)a; o1[i] = (short)b;
    }
    *(short8*)(d0) = o0;
    *(short8*)(d1) = o1;
    #pragma unroll
    for (int i = 0; i < 8; ++i) {
        unsigned short a, b;
        split2(acc[i + 8] * inv, a, b);
        o0[i] = (short)a; o1[i] = (short)b;
    }
    *(short8*)(d0 + 8) = o0;
    *(short8*)(d1 + 8) = o1;
}

// ---------------- launch ----------------
extern "C" void kernel_launch(void* const* d_in, const int* in_sizes, int n_in,
                              void* d_out, int out_size, void* d_ws, size_t ws_size,
                              hipStream_t stream)
{
    const float* x     = (const float*)d_in[0];
    const int*   ei    = (const int*)  d_in[1];
    const float* W_in  = (const float*)d_in[2];
    const float* b_in  = (const float*)d_in[3];
    const float* plas  = (const float*)d_in[4];
    const float* syn   = (const float*)d_in[5];
    const float* inpw  = (const float*)d_in[6];
    const float* inpb  = (const float*)d_in[7];
    const float* outpw = (const float*)d_in[8];
    const float* outpb = (const float*)d_in[9];
    const float* Wout  = (const float*)d_in[10];
    const float* bout  = (const float*)d_in[11];
    float* out = (float*)d_out;

    char* ws = (char*)d_ws;
    float* h    = (float*)(ws + 0);
    float* h2   = (float*)(ws + (8u  << 20));
    float* qkv  = (float*)(ws + (16u << 20));
    unsigned short* xc0  = (unsigned short*)(ws + (16u << 20));
    unsigned short* h2c0 = (unsigned short*)(ws + (8u  << 20));
    unsigned short* h2c1 = (unsigned short*)(ws + (12u << 20));
    unsigned short* h2c2 = (unsigned short*)(ws + (40u << 20));
    unsigned short* Wic  = (unsigned short*)(ws + (44u << 20));
    unsigned short* ipc  = (unsigned short*)(ws + (45u << 20));
    unsigned short* opc  = (unsigned short*)(ws + (16u << 20));
    unsigned short* woc  = (unsigned short*)(ws + (17u << 20));
    unsigned short* Kc0  = (unsigned short*)(ws + 0);
    unsigned short* Kc1  = (unsigned short*)(ws + (4u  << 20));
    unsigned short* Kc2  = (unsigned short*)(ws + (8u  << 20));
    unsigned short* Vt0  = (unsigned short*)(ws + (12u << 20));
    unsigned short* Op16 = (unsigned short*)(ws + (40u << 20));
    unsigned short* aOc0 = (unsigned short*)(ws + 0);
    unsigned short* aOc1 = (unsigned short*)(ws + (4u  << 20));
    unsigned short* tmpc0 = (unsigned short*)(ws + (8u  << 20));
    unsigned short* tmpc1 = (unsigned short*)(ws + (12u << 20));
    int*   rowp = (int*)(ws + (56u << 20));
    int*   curs = (int*)(ws + (56u << 20) + 40960);
    int*   esrc = (int*)(ws + (56u << 20) + 81920);
    float* Ml   = (float*)(ws + (56u << 20) + 81920);

    // CSR build
    hipMemsetAsync(curs, 0, N_NODES * sizeof(int), stream);
    hist_kernel<<<NEDGE / 256, 256, 0, stream>>>(ei, curs);
    scan_kernel<<<1, 1024, 0, stream>>>(curs, rowp, curs);
    scatter_kernel<<<NEDGE / 256, 256, 0, stream>>>(ei, curs, esrc);

    // pre-split inputs & pre-attn weights
    split_w_kernel<<<(HID * IND) / 2048, 256, 0, stream>>>(W_in, Wic, HID * IND);
    split_w_kernel<<<(768 * HID) / 2048, 256, 0, stream>>>(inpw, ipc, 768 * HID);
    split_w_kernel<<<(N_NODES * IND) / 2048, 256, 0, stream>>>(x, xc0, N_NODES * IND);

    // in-proj (6-term MFMA)
    mfma_gemm_kernel<6, 3, false><<<dim3(N_NODES / 64, HID / 64), 256, 0, stream>>>(
        xc0, xc0 + N_NODES * IND, xc0 + 2 * N_NODES * IND, Wic, b_in,
        h, nullptr, nullptr, N_NODES, HID, IND);

    // 3 GNN layers (float4 gathers; last layer emits split-3 bf16)
    aggregate4_kernel<0><<<2048, 256, 0, stream>>>(h,  h2, nullptr, nullptr, nullptr,
                                                   rowp, esrc, plas, syn, 0);
    aggregate4_kernel<0><<<2048, 256, 0, stream>>>(h2, h,  nullptr, nullptr, nullptr,
                                                   rowp, esrc, plas, syn, 1);
    aggregate4_kernel<1><<<2048, 256, 0, stream>>>(h, nullptr, h2c0, h2c1, h2c2,
                                                   rowp, esrc, plas, syn, 2);

    // qkv projection (6-term MFMA)
    mfma_gemm_kernel<6, 3, false><<<dim3(N_NODES / 64, 768 / 64), 256, 0, stream>>>(
        h2c0, h2c1, h2c2, ipc, inpb, qkv, nullptr, nullptr, N_NODES, 768, HID);

    // split pre-pass (K 3-comp, V transposed)
    split_kernel<<<dim3(N_NODES / 64, NHEAD), 256, 0, stream>>>(
        qkv, Kc0, Kc1, Kc2, Vt0);

    // pipelined MFMA attention: 128 q/block, split-K x2 (512 blocks, 2/CU)
    attn_pipe_kernel<<<dim3(N_NODES / 128, NHEAD, 2), 256, 0, stream>>>(
        qkv, Kc0, Kc1, Kc2, Vt0, Op16, Ml);

    // combine halves -> aO (split-2 bf16)
    combine_kernel<<<512, 256, 0, stream>>>(Op16, Ml, aOc0, aOc1);

    // post-attn weight splits (qkv region now dead)
    split_w_kernel<<<(HID * HID) / 2048, 256, 0, stream>>>(outpw, opc, HID * HID);
    split_w_kernel<<<(OUTD * HID) / 2048, 256, 0, stream>>>(Wout, woc, OUTD * HID);

    // output projections (3-term MFMA)
    mfma_gemm_kernel<3, 2, true><<<dim3(N_NODES / 64, HID / 64), 256, 0, stream>>>(
        aOc0, aOc1, nullptr, opc, outpb, nullptr, tmpc0, tmpc1, N_NODES, HID, HID);
    mfma_gemm_kernel<3, 2, false><<<dim3(N_NODES / 64, OUTD / 64), 256, 0, stream>>>(
        tmpc0, tmpc1, nullptr, woc, bout, out, nullptr, nullptr, N_NODES, OUTD, HID);
}